// Round 2
// baseline (484.897 us; speedup 1.0000x reference)
//
#include <hip/hip_runtime.h>
#include <hip/hip_bf16.h>

#define DEV __device__ __forceinline__

typedef __attribute__((ext_vector_type(8))) short short8;
typedef __attribute__((ext_vector_type(4))) float f32x4;

static constexpr int D_MODEL = 1024;
static constexpr int NEXP = 8;
static constexpr int N_TOK = 4096;
static constexpr int CAP = 512;

DEV unsigned short f2bf(float f) {
  union { float f; unsigned u; } v; v.f = f;
  unsigned r = v.u + 0x7FFFu + ((v.u >> 16) & 1u);
  return (unsigned short)(r >> 16);
}

DEV float gelu_tanh(float v) {
  // jax.nn.gelu(approximate=True)
  const float c = 0.7978845608028654f;
  float u = c * (v + 0.044715f * v * v * v);
  float ex = __expf(2.0f * u);
  float t = 1.0f - 2.0f / (ex + 1.0f);
  return 0.5f * v * (1.0f + t);
}

typedef const __attribute__((address_space(1))) void* gas_ptr;
typedef __attribute__((address_space(3))) void* las_ptr;
DEV void gload_lds16(const void* g, void* l) {
  __builtin_amdgcn_global_load_lds((gas_ptr)g, (las_ptr)l, 16, 0, 0);
}

// ---------------- Router: logits in fp64, top-2, softmax gates ----------------
__global__ __launch_bounds__(256) void router_kernel(
    const float* __restrict__ x, const float* __restrict__ hk,
    int* __restrict__ idx, float* __restrict__ gates)
{
  const int n = blockIdx.x;
  const int tid = threadIdx.x;
  const int lane = tid & 63, wid = tid >> 6;
  float4 xv = ((const float4*)(x + (long)n * D_MODEL))[tid];
  double acc[NEXP];
#pragma unroll
  for (int e = 0; e < NEXP; e++) acc[e] = 0.0;
  const int d0 = tid * 4;
#pragma unroll
  for (int j = 0; j < 4; j++) {
    float xs = (&xv.x)[j];
    const float4* h = (const float4*)(hk + (long)(d0 + j) * NEXP);
    float4 h0 = h[0], h1 = h[1];
    acc[0] += (double)xs * h0.x; acc[1] += (double)xs * h0.y;
    acc[2] += (double)xs * h0.z; acc[3] += (double)xs * h0.w;
    acc[4] += (double)xs * h1.x; acc[5] += (double)xs * h1.y;
    acc[6] += (double)xs * h1.z; acc[7] += (double)xs * h1.w;
  }
#pragma unroll
  for (int off = 32; off > 0; off >>= 1) {
#pragma unroll
    for (int e = 0; e < NEXP; e++) acc[e] += __shfl_down(acc[e], off);
  }
  __shared__ double red[4][NEXP];
  if (lane == 0) {
#pragma unroll
    for (int e = 0; e < NEXP; e++) red[wid][e] = acc[e];
  }
  __syncthreads();
  if (tid == 0) {
    double lg[NEXP];
#pragma unroll
    for (int e = 0; e < NEXP; e++) lg[e] = red[0][e] + red[1][e] + red[2][e] + red[3][e];
    int i0 = 0;
    for (int e = 1; e < NEXP; e++) if (lg[e] > lg[i0]) i0 = e;   // tie -> lowest idx
    int i1 = (i0 == 0) ? 1 : 0;
    for (int e = 0; e < NEXP; e++) { if (e == i0) continue; if (lg[e] > lg[i1]) i1 = e; }
    float dl = (float)(lg[i1] - lg[i0]);   // <= 0
    float ex = __expf(dl);
    idx[n * 2] = i0; idx[n * 2 + 1] = i1;
    gates[n * 2] = 1.0f / (1.0f + ex);
    gates[n * 2 + 1] = ex / (1.0f + ex);
  }
}

// ------------- Scan: per-(k,e)-stream ranks via ballot, capacity mask -------------
__global__ __launch_bounds__(1024) void scan_kernel(
    const int* __restrict__ idx, int* __restrict__ slots, int* __restrict__ tokslot)
{
  const int tid = threadIdx.x;
  for (int i = tid; i < NEXP * CAP * 2; i += 1024) tokslot[i] = -1;
  __syncthreads();
  const int w = tid >> 6, lane = tid & 63;
  const int k = w >> 3, e = w & 7;          // 16 waves = 2 k-streams x 8 experts
  const unsigned long long ltmask = (1ull << lane) - 1ull;
  int running = 0;
  for (int c = 0; c < N_TOK / 64; c++) {
    int t = c * 64 + lane;
    bool match = (idx[t * 2 + k] == e);
    unsigned long long m = __ballot(match);
    if (match) {
      int pos = running + (int)__popcll(m & ltmask);
      int s = (pos < CAP) ? pos : -1;
      slots[t * 2 + k] = s;
      if (s >= 0) tokslot[((e << 9) + s) * 2 + k] = t;
    }
    running += (int)__popcll(m);
  }
}

// ------------- Gather: Xe[e][c][:] = bf16( x[tok0] + x[tok1] ) -------------
__global__ __launch_bounds__(256) void gather_kernel(
    const float* __restrict__ x, const int* __restrict__ tokslot,
    unsigned short* __restrict__ Xe)
{
  const int wid = threadIdx.x >> 6, lane = threadIdx.x & 63;
  const int s = blockIdx.x * 4 + wid;
  const int t0 = tokslot[s * 2], t1 = tokslot[s * 2 + 1];
  const float4* p0 = (t0 >= 0) ? (const float4*)(x + (long)t0 * D_MODEL) : nullptr;
  const float4* p1 = (t1 >= 0) ? (const float4*)(x + (long)t1 * D_MODEL) : nullptr;
  unsigned out[8];
#pragma unroll
  for (int j = 0; j < 4; j++) {
    int q = lane * 4 + j;
    float4 v = {0.f, 0.f, 0.f, 0.f};
    if (p0) { float4 a = p0[q]; v.x += a.x; v.y += a.y; v.z += a.z; v.w += a.w; }
    if (p1) { float4 a = p1[q]; v.x += a.x; v.y += a.y; v.z += a.z; v.w += a.w; }
    out[j * 2]     = (unsigned)f2bf(v.x) | ((unsigned)f2bf(v.y) << 16);
    out[j * 2 + 1] = (unsigned)f2bf(v.z) | ((unsigned)f2bf(v.w) << 16);
  }
  uint4* dst = (uint4*)(Xe + (long)s * D_MODEL + lane * 16);
  dst[0] = make_uint4(out[0], out[1], out[2], out[3]);
  dst[1] = make_uint4(out[4], out[5], out[6], out[7]);
}

// ------------- GEMM: [E] x (M x K bf16) x (K x N f32, transposed in-flight) -------------
// 128x128 tile, 4 waves (2x2), BK=64, mfma_f32_16x16x32_bf16.
// LDS tiles [row][64 k] bf16, row stride 128B, chunk swizzle: phys = log ^ ((row>>1)&7).
// A staged via global_load_lds (16B, linear dst, swizzle pre-applied to global src).
// B (f32 [K][N]) loaded coalesced, converted to bf16, transpose-written via ds_write_b128.
template<bool GELU, bool BF16OUT>
__global__ __launch_bounds__(256) void moe_gemm_kernel(
    const unsigned short* __restrict__ A,  // [E][M][K] bf16
    const float* __restrict__ B,           // [E][K][N] f32
    void* __restrict__ OutV,               // [E][M][N] bf16 or f32
    int M, int N, int K)
{
  __shared__ __align__(16) char lds[32768];
  char* As = lds;            // 128 rows x 128B
  char* Bs = lds + 16384;    // 128 n-rows x 128B
  const int tid = threadIdx.x;
  const int lane = tid & 63;
  const int wid = tid >> 6;
  const int wm = wid >> 1, wn = wid & 1;
  const int ex = blockIdx.z;
  const long m0 = (long)blockIdx.y * 128;
  const long n0 = (long)blockIdx.x * 128;
  const unsigned short* Ae = A + (long)ex * M * K;
  const float* Be = B + (long)ex * K * N;

  f32x4 acc[4][4];
#pragma unroll
  for (int i = 0; i < 4; i++)
#pragma unroll
    for (int j = 0; j < 4; j++) acc[i][j] = (f32x4){0.f, 0.f, 0.f, 0.f};

  // ---- A staging: 4 x 16B per thread per K-step; linear LDS dst, swizzled src
  const unsigned short* agp[4];
  char* aldst[4];
#pragma unroll
  for (int i = 0; i < 4; i++) {
    int row = i * 32 + wid * 8 + (lane >> 3);
    int phys = lane & 7;
    int logc = phys ^ ((row >> 1) & 7);
    aldst[i] = As + i * 4096 + wid * 1024 + lane * 16;
    agp[i] = Ae + (m0 + row) * (long)K + logc * 8;
  }

  // ---- B staging: thread (nq, kq8): 8 k-rows x 4 n f32
  const int nq = tid & 31, kq8 = tid >> 5;
  const float* bbase = Be + (long)(kq8 * 8) * N + n0 + nq * 4;
  unsigned bwoff[4];
#pragma unroll
  for (int nn = 0; nn < 4; nn++) {
    int n = nq * 4 + nn;
    int phys = kq8 ^ ((n >> 1) & 7);
    bwoff[nn] = n * 128 + phys * 16;
  }

  // ---- fragment read offsets (per h-half added later)
  unsigned aro[4], bro[4];
#pragma unroll
  for (int f = 0; f < 4; f++) {
    int row = wm * 64 + f * 16 + (lane & 15);
    aro[f] = row * 128 + (((lane >> 4) ^ ((row >> 1) & 7)) * 16);
    int nrow = wn * 64 + f * 16 + (lane & 15);
    bro[f] = nrow * 128 + (((lane >> 4) ^ ((nrow >> 1) & 7)) * 16);
  }
  // XOR with (4^..) to flip logical chunk by +4 for the second k-half:
  // phys(log^4) = phys(log) ^ 4 (swizzle XOR commutes), i.e. byte offset ^ 64.

  const int ksteps = K >> 6;
  for (int ks = 0; ks < ksteps; ks++) {
    const long k0 = (long)ks << 6;
    // B global loads (coalesced dwordx4, 8 k-rows)
    float4 bl[8];
#pragma unroll
    for (int kk = 0; kk < 8; kk++) bl[kk] = *(const float4*)(bbase + (k0 + kk) * N);
    // A async direct-to-LDS
#pragma unroll
    for (int i = 0; i < 4; i++) gload_lds16(agp[i] + k0, aldst[i]);
    // convert + transposed swizzled store of B
#pragma unroll
    for (int nn = 0; nn < 4; nn++) {
      uint4 wv;
      wv.x = (unsigned)f2bf((&bl[0].x)[nn]) | ((unsigned)f2bf((&bl[1].x)[nn]) << 16);
      wv.y = (unsigned)f2bf((&bl[2].x)[nn]) | ((unsigned)f2bf((&bl[3].x)[nn]) << 16);
      wv.z = (unsigned)f2bf((&bl[4].x)[nn]) | ((unsigned)f2bf((&bl[5].x)[nn]) << 16);
      wv.w = (unsigned)f2bf((&bl[6].x)[nn]) | ((unsigned)f2bf((&bl[7].x)[nn]) << 16);
      *(uint4*)(Bs + bwoff[nn]) = wv;
    }
    __syncthreads();
#pragma unroll
    for (int h = 0; h < 2; h++) {
      const unsigned hx = h * 64;   // logical chunk +4 == byte ^ 64 (swizzle commutes)
      short8 af[4], bf[4];
#pragma unroll
      for (int f = 0; f < 4; f++) {
        af[f] = *(const short8*)(As + (aro[f] ^ hx));
        bf[f] = *(const short8*)(Bs + (bro[f] ^ hx));
      }
#pragma unroll
      for (int mf = 0; mf < 4; mf++)
#pragma unroll
        for (int nf = 0; nf < 4; nf++)
          acc[mf][nf] = __builtin_amdgcn_mfma_f32_16x16x32_bf16(af[mf], bf[nf], acc[mf][nf], 0, 0, 0);
    }
    __syncthreads();
  }

  // epilogue: C/D layout col = lane&15, row = (lane>>4)*4 + r
  const long colb = n0 + wn * 64 + (lane & 15);
  const long rowb = m0 + wm * 64 + ((lane >> 4) << 2);
  if constexpr (BF16OUT) {
    unsigned short* O = (unsigned short*)OutV + (long)ex * M * N;
#pragma unroll
    for (int mf = 0; mf < 4; mf++)
#pragma unroll
      for (int nf = 0; nf < 4; nf++)
#pragma unroll
        for (int r = 0; r < 4; r++) {
          float v = acc[mf][nf][r];
          if constexpr (GELU) v = gelu_tanh(v);
          O[(rowb + mf * 16 + r) * (long)N + colb + nf * 16] = f2bf(v);
        }
  } else {
    float* O = (float*)OutV + (long)ex * M * N;
#pragma unroll
    for (int mf = 0; mf < 4; mf++)
#pragma unroll
      for (int nf = 0; nf < 4; nf++)
#pragma unroll
        for (int r = 0; r < 4; r++) {
          float v = acc[mf][nf][r];
          if constexpr (GELU) v = gelu_tanh(v);
          O[(rowb + mf * 16 + r) * (long)N + colb + nf * 16] = v;
        }
  }
}

// ------------- Combine: out[n] = sum_k valid gate_k * Y[e_k][slot_k] -------------
__global__ __launch_bounds__(256) void combine_kernel(
    const float* __restrict__ Y, const int* __restrict__ idx,
    const int* __restrict__ slots, const float* __restrict__ gates,
    float* __restrict__ out)
{
  const int n = blockIdx.x, tid = threadIdx.x;
  const int e0 = idx[n * 2], e1 = idx[n * 2 + 1];
  const int s0 = slots[n * 2], s1 = slots[n * 2 + 1];
  const float g0 = gates[n * 2], g1 = gates[n * 2 + 1];
  float4 a = {0.f, 0.f, 0.f, 0.f};
  if (s0 >= 0) {
    float4 v = ((const float4*)(Y + ((long)e0 * CAP + s0) * D_MODEL))[tid];
    a.x += g0 * v.x; a.y += g0 * v.y; a.z += g0 * v.z; a.w += g0 * v.w;
  }
  if (s1 >= 0) {
    float4 v = ((const float4*)(Y + ((long)e1 * CAP + s1) * D_MODEL))[tid];
    a.x += g1 * v.x; a.y += g1 * v.y; a.z += g1 * v.z; a.w += g1 * v.w;
  }
  ((float4*)(out + (long)n * D_MODEL))[tid] = a;
}

extern "C" void kernel_launch(void* const* d_in, const int* in_sizes, int n_in,
                              void* d_out, int out_size, void* d_ws, size_t ws_size,
                              hipStream_t stream)
{
  const float* x  = (const float*)d_in[0];
  const float* hk = (const float*)d_in[1];
  const float* w1 = (const float*)d_in[2];
  const float* w2 = (const float*)d_in[3];
  float* out = (float*)d_out;
  char* ws = (char*)d_ws;

  int*   idx     = (int*)(ws + 0);                         // 32 KB
  float* gates   = (float*)(ws + 32768);                   // 32 KB
  int*   slots   = (int*)(ws + 65536);                     // 32 KB
  int*   tokslot = (int*)(ws + 98304);                     // 32 KB
  unsigned short* Xe = (unsigned short*)(ws + 131072);                  // 8 MB
  unsigned short* H  = (unsigned short*)(ws + 131072 + 8388608);        // 32 MB
  float* Y = (float*)(ws + 131072 + 8388608 + 33554432);                // 16 MB

  router_kernel<<<N_TOK, 256, 0, stream>>>(x, hk, idx, gates);
  scan_kernel<<<1, 1024, 0, stream>>>(idx, slots, tokslot);
  gather_kernel<<<NEXP * CAP / 4, 256, 0, stream>>>(x, tokslot, Xe);
  moe_gemm_kernel<true, true><<<dim3(4096 / 128, 512 / 128, NEXP), 256, 0, stream>>>(
      Xe, w1, H, 512, 4096, 1024);
  moe_gemm_kernel<false, false><<<dim3(1024 / 128, 512 / 128, NEXP), 256, 0, stream>>>(
      H, w2, Y, 512, 1024, 4096);
  combine_kernel<<<N_TOK, 256, 0, stream>>>(Y, idx, slots, gates, out);
}